// Round 2
// baseline (400.531 us; speedup 1.0000x reference)
//
#include <hip/hip_runtime.h>
#include <hip/hip_cooperative_groups.h>

namespace cg = cooperative_groups;

#define NB 32
#define NC 511      // T-1 context positions
#define NK 8        // senses (center)
#define NS 8        // senses (context)
#define ND 300      // embedding dim
#define ND4 75      // float4 per row
#define NCH 8       // c-chunks for m partials
#define CCHUNK 64
#define EPS_COS 1e-8f

// Single cooperative kernel, 256 blocks x 512 threads (8 waves = 2/SIMD, 1 block/CU).
// P1: v = mean_s ctx, a = <cen, v>/sqrt(d)     (block = (b, c-group of 64))
// P2: softmax over c per (b,k), in place       (block = (b,k))
// P3: m-partials over c-chunks                 (block = (b,ch))
// P4: reduce partials + cosine sim -> s[b,k]   (block = (b,k))
// P5: softmax q, argmax, pooled copy           (block = b, first 32 blocks)
// Positional log-weight is constant (dist>=1 -> exp(-1000d) underflows -> log(eps)),
// cancels in P2's softmax; center_pos / query_token_ids unused.
__global__ __launch_bounds__(512, 1) void fused(const float* __restrict__ ctx,
                                                const float* __restrict__ cen,
                                                float* __restrict__ v,
                                                float* __restrict__ a,
                                                float* __restrict__ part,
                                                float* __restrict__ s,
                                                float* __restrict__ out) {
    cg::grid_group grid = cg::this_grid();
    const int t = threadIdx.x;
    const int lane = t & 63;
    const int w = t >> 6;          // wave 0..7
    const int blk = blockIdx.x;    // 0..255

    __shared__ float sh_al[NK][CCHUNK];   // 2 KB, P3 alpha tile
    __shared__ float sh_red[8];           // wave partials
    __shared__ float sh_red3[8][3];       // P4 3-value reduce
    __shared__ int   sh_idx;

    // ---------------- P1: v and a ----------------
    {
        const int b = blk >> 3;
        const int cbase = (blk & 7) * 64 + w * 8;
        const float4* cen4 = (const float4*)cen + (size_t)b * NK * ND4;
        const int i0 = lane;
        const int i1 = lane + 64;
        const bool has1 = (i1 < ND4);

#pragma unroll 1
        for (int u = 0; u < 8; ++u) {
            const int c = cbase + u;
            if (c >= NC) continue;   // wave-uniform (only the very last slot)

            const float4* ctx4 = (const float4*)ctx + (size_t)(b * NC + c) * NS * ND4;
            float4 s0 = make_float4(0.f, 0.f, 0.f, 0.f);
            float4 s1 = make_float4(0.f, 0.f, 0.f, 0.f);
#pragma unroll
            for (int sj = 0; sj < NS; ++sj) {
                float4 x = ctx4[sj * ND4 + i0];
                s0.x += x.x; s0.y += x.y; s0.z += x.z; s0.w += x.w;
                if (has1) {
                    float4 y = ctx4[sj * ND4 + i1];
                    s1.x += y.x; s1.y += y.y; s1.z += y.z; s1.w += y.w;
                }
            }
            const float inv = 0.125f;
            s0.x *= inv; s0.y *= inv; s0.z *= inv; s0.w *= inv;
            s1.x *= inv; s1.y *= inv; s1.z *= inv; s1.w *= inv;

            float4* v4 = (float4*)v + (size_t)(b * NC + c) * ND4;
            v4[i0] = s0;
            if (has1) v4[i1] = s1;

            float pk[NK];
#pragma unroll
            for (int k = 0; k < NK; ++k) {
                float4 ca = cen4[k * ND4 + i0];
                float p = ca.x * s0.x + ca.y * s0.y + ca.z * s0.z + ca.w * s0.w;
                if (has1) {
                    float4 cb = cen4[k * ND4 + i1];
                    p += cb.x * s1.x + cb.y * s1.y + cb.z * s1.z + cb.w * s1.w;
                }
                pk[k] = p;
            }
#pragma unroll
            for (int off = 32; off; off >>= 1) {
#pragma unroll
                for (int k = 0; k < NK; ++k) pk[k] += __shfl_down(pk[k], off);
            }
            if (lane == 0) {
                const float scale = 0.057735026919f; // 1/sqrt(300)
#pragma unroll
                for (int k = 0; k < NK; ++k)
                    a[(size_t)(b * NK + k) * NC + c] = pk[k] * scale;
            }
        }
    }
    grid.sync();

    // ---------------- P2: softmax over c per (b,k) ----------------
    {
        float* p = a + (size_t)blk * NC;
        float x = (t < NC) ? p[t] : -INFINITY;
        float mx = x;
#pragma unroll
        for (int off = 32; off; off >>= 1) mx = fmaxf(mx, __shfl_xor(mx, off));
        if (lane == 0) sh_red[w] = mx;
        __syncthreads();
        mx = sh_red[0];
#pragma unroll
        for (int i = 1; i < 8; ++i) mx = fmaxf(mx, sh_red[i]);

        float e = (t < NC) ? __expf(x - mx) : 0.f;
        float ss = e;
#pragma unroll
        for (int off = 32; off; off >>= 1) ss += __shfl_xor(ss, off);
        __syncthreads();
        if (lane == 0) sh_red[w] = ss;
        __syncthreads();
        float tot = sh_red[0];
#pragma unroll
        for (int i = 1; i < 8; ++i) tot += sh_red[i];
        if (t < NC) p[t] = e * (1.f / tot);
    }
    grid.sync();

    // ---------------- P3: m partials over c-chunks ----------------
    {
        const int b = blk >> 3;
        const int ch = blk & 7;
        const int c0 = ch * CCHUNK;
        const int cn = min(CCHUNK, NC - c0);
        {   // NK*CCHUNK == 512 == blockDim
            const int k = t >> 6;
            const int cc = t & 63;
            sh_al[k][cc] = (cc < cn) ? a[(size_t)(b * NK + k) * NC + c0 + cc] : 0.f;
        }
        __syncthreads();
        if (t < ND) {
            float acc[NK] = {0.f, 0.f, 0.f, 0.f, 0.f, 0.f, 0.f, 0.f};
            const float* vp = v + ((size_t)b * NC + c0) * ND + t;
            for (int cc = 0; cc < cn; ++cc) {
                float vv = vp[(size_t)cc * ND];
#pragma unroll
                for (int k = 0; k < NK; ++k) acc[k] += sh_al[k][cc] * vv;
            }
            float* pp = part + ((size_t)(ch * NB + b) * NK) * ND + t;
#pragma unroll
            for (int k = 0; k < NK; ++k) pp[(size_t)k * ND] = acc[k];
        }
    }
    grid.sync();

    // ---------------- P4: reduce partials + cosine -> s[b,k] ----------------
    {
        const int b = blk >> 3;
        const int k = blk & 7;
        float num = 0.f, n1 = 0.f, n2 = 0.f;
        if (t < ND) {
            float m = 0.f;
#pragma unroll
            for (int ch = 0; ch < NCH; ++ch)
                m += part[((size_t)(ch * NB + b) * NK + k) * ND + t];
            float cv = cen[(size_t)(b * NK + k) * ND + t];
            num = cv * m; n1 = cv * cv; n2 = m * m;
        }
#pragma unroll
        for (int off = 32; off; off >>= 1) {
            num += __shfl_down(num, off);
            n1  += __shfl_down(n1, off);
            n2  += __shfl_down(n2, off);
        }
        if (lane == 0) { sh_red3[w][0] = num; sh_red3[w][1] = n1; sh_red3[w][2] = n2; }
        __syncthreads();
        if (t == 0) {
            float a0 = 0.f, a1 = 0.f, a2 = 0.f;
#pragma unroll
            for (int i = 0; i < 8; ++i) { a0 += sh_red3[i][0]; a1 += sh_red3[i][1]; a2 += sh_red3[i][2]; }
            float denom = fmaxf(sqrtf(a1), EPS_COS) * fmaxf(sqrtf(a2), EPS_COS);
            s[b * NK + k] = a0 / denom;
        }
    }
    grid.sync();

    // ---------------- P5: q softmax + argmax + pooled ----------------
    if (blk < NB) {
        const int b = blk;
        if (t == 0) {
            float sv[NK];
#pragma unroll
            for (int k = 0; k < NK; ++k) sv[k] = s[b * NK + k];
            float mx = sv[0];
#pragma unroll
            for (int k = 1; k < NK; ++k) mx = fmaxf(mx, sv[k]);
            float e[NK], sum = 0.f;
#pragma unroll
            for (int k = 0; k < NK; ++k) { e[k] = __expf(sv[k] - mx); sum += e[k]; }
            float invs = 1.f / sum;
            int best = 0; float bv = sv[0];
#pragma unroll
            for (int k = 1; k < NK; ++k) if (sv[k] > bv) { bv = sv[k]; best = k; }
#pragma unroll
            for (int k = 0; k < NK; ++k)
                out[(size_t)NB * ND + b * NK + k] = e[k] * invs;
            sh_idx = best;
        }
        __syncthreads();
        const float* src = cen + (size_t)(b * NK + sh_idx) * ND;
        for (int idx = t; idx < ND; idx += 512)
            out[(size_t)b * ND + idx] = src[idx];
    }
}

extern "C" void kernel_launch(void* const* d_in, const int* in_sizes, int n_in,
                              void* d_out, int out_size, void* d_ws, size_t ws_size,
                              hipStream_t stream) {
    // d_in[0]=center_pos, d_in[1]=query_token_ids: unused (log-weight constant)
    const float* cen = (const float*)d_in[2];   // [B,K,d]
    const float* ctx = (const float*)d_in[3];   // [B,C,S,d]
    float* out = (float*)d_out;                 // pooled [B,d] then q [B,K]

    float* v    = (float*)d_ws;                      // B*C*D
    float* a    = v + (size_t)NB * NC * ND;          // B*K*C
    float* part = a + (size_t)NB * NK * NC;          // NCH*B*K*D
    float* s    = part + (size_t)NCH * NB * NK * ND; // B*K

    void* args[] = { (void*)&ctx, (void*)&cen, (void*)&v, (void*)&a,
                     (void*)&part, (void*)&s, (void*)&out };
    hipLaunchCooperativeKernel((void*)fused, dim3(256), dim3(512), args, 0, stream);
}

// Round 3
// 256.098 us; speedup vs baseline: 1.5640x; 1.5640x over previous
//
#include <hip/hip_runtime.h>

#define NB 32
#define NC 511      // T-1 context positions
#define NK 8        // senses (center)
#define NS 8        // senses (context)
#define ND 300      // embedding dim
#define ND4 75      // float4 per row
#define NCH 16      // c-chunks for m-tilde partials
#define CCHUNK 32
#define EPS_COS 1e-8f

// Math notes (verified R1/R2, absmax 0.0):
//  - positional log-weight is a constant (dist>=1 -> exp(-1000*d) underflows
//    -> log(EPS)), cancels in softmax over c => center_pos/query_token_ids unused.
//  - cosine(cen, m) is scale-invariant in m => softmax normalization (and the
//    max-subtraction; |a| <~ 2) cancels entirely. K1 emits ea = exp(a/sqrt(d))
//    and we accumulate unnormalized m~ = sum_c ea * v. No softmax kernel.

// ---------------------------------------------------------------------------
// K1: one wave per (b,c). v = mean_s ctx[b,c,s,:]; ea[b,k,c] = exp(<cen_k,v>/sqrt(d)).
// Reads ctx once (157 MB) — the dominant traffic; BW-bound.
// ---------------------------------------------------------------------------
__global__ __launch_bounds__(256) void k_va(const float* __restrict__ ctx,
                                            const float* __restrict__ cen,
                                            float* __restrict__ v,
                                            float* __restrict__ ea) {
    int b    = blockIdx.x >> 7;        // 128 blocks per b
    int cgrp = blockIdx.x & 127;
    int w    = threadIdx.x >> 6;       // 4 waves -> 4 c's
    int lane = threadIdx.x & 63;
    int c = cgrp * 4 + w;
    if (c >= NC) return;               // wave-uniform

    const float4* ctx4 = (const float4*)ctx + (size_t)(b * NC + c) * NS * ND4;
    int i0 = lane;
    int i1 = lane + 64;
    bool has1 = (i1 < ND4);            // lanes 0..10 own a second float4

    float4 s0 = make_float4(0.f, 0.f, 0.f, 0.f);
    float4 s1 = make_float4(0.f, 0.f, 0.f, 0.f);
#pragma unroll
    for (int s = 0; s < NS; ++s) {
        float4 x = ctx4[s * ND4 + i0];
        s0.x += x.x; s0.y += x.y; s0.z += x.z; s0.w += x.w;
        if (has1) {
            float4 y = ctx4[s * ND4 + i1];
            s1.x += y.x; s1.y += y.y; s1.z += y.z; s1.w += y.w;
        }
    }
    const float inv = 0.125f;   // 1/S
    s0.x *= inv; s0.y *= inv; s0.z *= inv; s0.w *= inv;
    s1.x *= inv; s1.y *= inv; s1.z *= inv; s1.w *= inv;

    float4* v4 = (float4*)v + (size_t)(b * NC + c) * ND4;
    v4[i0] = s0;
    if (has1) v4[i1] = s1;

    const float4* cen4 = (const float4*)cen + (size_t)b * NK * ND4;
    float pk[NK];
#pragma unroll
    for (int k = 0; k < NK; ++k) {
        float4 ca = cen4[k * ND4 + i0];
        float p = ca.x * s0.x + ca.y * s0.y + ca.z * s0.z + ca.w * s0.w;
        if (has1) {
            float4 cb = cen4[k * ND4 + i1];
            p += cb.x * s1.x + cb.y * s1.y + cb.z * s1.z + cb.w * s1.w;
        }
        pk[k] = p;
    }
#pragma unroll
    for (int off = 32; off; off >>= 1) {
#pragma unroll
        for (int k = 0; k < NK; ++k) pk[k] += __shfl_down(pk[k], off);
    }
    if (lane == 0) {
        const float scale = 0.057735026919f; // 1/sqrt(300)
#pragma unroll
        for (int k = 0; k < NK; ++k)
            ea[(size_t)(b * NK + k) * NC + c] = __expf(pk[k] * scale);
    }
}

// ---------------------------------------------------------------------------
// K2: m~ partials over c-chunks: part[ch,b,k,:] = sum_{c in chunk} ea * v[b,c,:].
// 512 blocks (2/CU) for latency hiding; ea tile in LDS (broadcast reads).
// ---------------------------------------------------------------------------
__global__ __launch_bounds__(320) void k_m(const float* __restrict__ v,
                                           const float* __restrict__ ea,
                                           float* __restrict__ part) {
    int b  = blockIdx.x >> 4;
    int ch = blockIdx.x & 15;
    int c0 = ch * CCHUNK;
    int cn = min(CCHUNK, NC - c0);
    __shared__ float al[NK][CCHUNK];
    int t = threadIdx.x;
    if (t < NK * CCHUNK) {             // 256 loads
        int k = t >> 5, cc = t & 31;
        al[k][cc] = (cc < cn) ? ea[(size_t)(b * NK + k) * NC + c0 + cc] : 0.f;
    }
    __syncthreads();
    if (t < ND) {
        float acc[NK] = {0.f, 0.f, 0.f, 0.f, 0.f, 0.f, 0.f, 0.f};
        const float* vp = v + ((size_t)b * NC + c0) * ND + t;
        for (int cc = 0; cc < cn; ++cc) {
            float vv = vp[(size_t)cc * ND];
#pragma unroll
            for (int k = 0; k < NK; ++k) acc[k] += al[k][cc] * vv;
        }
        float* pp = part + ((size_t)(ch * NB + b) * NK) * ND + t;
#pragma unroll
        for (int k = 0; k < NK; ++k) pp[(size_t)k * ND] = acc[k];
    }
}

// ---------------------------------------------------------------------------
// K3: per b — sum m~ partials into LDS, cosine per k (wave w: k=w, w+4),
// q softmax, first-max argmax, write q and pooled.
// ---------------------------------------------------------------------------
__global__ __launch_bounds__(256) void k_final(const float* __restrict__ part,
                                               const float* __restrict__ cen,
                                               float* __restrict__ out) {
    int b = blockIdx.x;
    __shared__ float m[NK * ND];
    __shared__ float sred[NK];
    __shared__ int bidx;
    int t = threadIdx.x;

    for (int idx = t; idx < NK * ND; idx += 256) {
        float s = 0.f;
#pragma unroll
        for (int ch = 0; ch < NCH; ++ch)
            s += part[(size_t)(ch * NB + b) * NK * ND + idx];
        m[idx] = s;
    }
    __syncthreads();

    int w = t >> 6, lane = t & 63;
#pragma unroll
    for (int kk = 0; kk < 2; ++kk) {
        int k = w + kk * 4;
        const float* cp = cen + (size_t)(b * NK + k) * ND;
        const float* mp = m + k * ND;
        float num = 0.f, n1 = 0.f, n2 = 0.f;
        for (int dd = lane; dd < ND; dd += 64) {
            float cv = cp[dd], mv = mp[dd];
            num += cv * mv; n1 += cv * cv; n2 += mv * mv;
        }
#pragma unroll
        for (int off = 32; off; off >>= 1) {
            num += __shfl_down(num, off);
            n1  += __shfl_down(n1, off);
            n2  += __shfl_down(n2, off);
        }
        if (lane == 0) {
            float denom = fmaxf(sqrtf(n1), EPS_COS) * fmaxf(sqrtf(n2), EPS_COS);
            sred[k] = num / denom;
        }
    }
    __syncthreads();

    if (t == 0) {
        float mx = sred[0];
#pragma unroll
        for (int k = 1; k < NK; ++k) mx = fmaxf(mx, sred[k]);
        float e[NK], sum = 0.f;
#pragma unroll
        for (int k = 0; k < NK; ++k) { e[k] = __expf(sred[k] - mx); sum += e[k]; }
        float inv = 1.f / sum;
        int best = 0; float bv = sred[0];
#pragma unroll
        for (int k = 1; k < NK; ++k) if (sred[k] > bv) { bv = sred[k]; best = k; }
#pragma unroll
        for (int k = 0; k < NK; ++k)
            out[(size_t)NB * ND + b * NK + k] = e[k] * inv;
        bidx = best;
    }
    __syncthreads();

    const float* src = cen + (size_t)(b * NK + bidx) * ND;
    for (int idx = t; idx < ND; idx += 256)
        out[(size_t)b * ND + idx] = src[idx];
}

extern "C" void kernel_launch(void* const* d_in, const int* in_sizes, int n_in,
                              void* d_out, int out_size, void* d_ws, size_t ws_size,
                              hipStream_t stream) {
    // d_in[0]=center_pos, d_in[1]=query_token_ids: unused (log-weight constant)
    const float* cen = (const float*)d_in[2];   // [B,K,d]
    const float* ctx = (const float*)d_in[3];   // [B,C,S,d]
    float* out = (float*)d_out;                 // pooled [B,d] then q [B,K]

    float* v    = (float*)d_ws;                      // B*C*D    floats
    float* ea   = v + (size_t)NB * NC * ND;          // B*K*C    floats
    float* part = ea + (size_t)NB * NK * NC;         // NCH*B*K*D floats (~4.9 MB)

    k_va<<<dim3(NB * 128), dim3(256), 0, stream>>>(ctx, cen, v, ea);
    k_m<<<dim3(NB * NCH), dim3(320), 0, stream>>>(v, ea, part);
    k_final<<<dim3(NB), dim3(256), 0, stream>>>(part, cen, out);
}